// Round 11
// baseline (260.016 us; speedup 1.0000x reference)
//
#include <hip/hip_runtime.h>

// TriAffine: S[b,x,y,z] = sum_{i,k,j} xb[b,x,i] z[b,z,k] W[i,k,j] yb[b,y,j]
// B=2, L=256, N_IN=128. Output [2,256,256,256] f32 (134 MB).
//
// SINGLE persistent kernel (512 blocks x 512 thr, exactly 2/CU co-resident):
//  phase1: blocks 0..271: W tile -> LDS (33-reg batch loads) + flat GEMM
//          A2[bx][n'] (x read direct from global f32, inline cvt; n'=k*136+j).
//          blocks 272..335: y,z f32 -> bf16. Others idle to barrier.
//  grid barrier: atomicAdd + agent-scope acquire spin (threadfence both sides;
//          bar zeroed per-call by hipMemsetAsync; fails safe if pre-counted).
//  phase2: stage2 body UNCHANGED from r8-r10 baseline; bx = blockIdx.x.
// Rationale: r10 showed one launch boundary ~ 17us; this removes the last one
// plus stage1f's 272-on-256 block tail (idle blocks wait at barrier, not queue).

typedef __bf16 bf16x8 __attribute__((ext_vector_type(8)));
typedef unsigned short ushort8_t __attribute__((ext_vector_type(8)));
typedef short short4_t __attribute__((ext_vector_type(4)));
typedef float f32x4 __attribute__((ext_vector_type(4)));
typedef unsigned short ushort4_t __attribute__((ext_vector_type(4)));

#define LL 256
#define NI 128
#define NFLATP 17408           // 128 * 136 (padded (k,j) axis)
#define KJ_STRIDE 136          // j-stride within A2 row / LDS
#define P_STRIDE 132           // P' LDS k-stride (264B)
#define NBLK 512

__device__ __forceinline__ unsigned short f2bf(float f) {
    unsigned u = __builtin_bit_cast(unsigned, f);
    u += 0x7FFFu + ((u >> 16) & 1u);   // RNE
    return (unsigned short)(u >> 16);
}
__device__ __forceinline__ float bf2f(unsigned short h) {
    return __builtin_bit_cast(float, (unsigned)h << 16);
}

__global__ __launch_bounds__(512, 4) void fused_kernel(const float* __restrict__ W,
                                                       const float* __restrict__ x,
                                                       const float* __restrict__ y,
                                                       const float* __restrict__ z,
                                                       unsigned short* __restrict__ yzbf,
                                                       unsigned short* __restrict__ A2g,
                                                       float* __restrict__ out,
                                                       unsigned* bar) {
    const int blk = blockIdx.x, tid = threadIdx.x;
    __shared__ __align__(16) unsigned short SH[LL * P_STRIDE];   // 67584 B (T aliases in phase1)

    const int wv = tid >> 6, lane = tid & 63;
    const int l15 = lane & 15, h = lane >> 4;

    // ================= PHASE 1 =================
    if (blk < 272) {
        // ---- W stage: SH as T[128][136]; all 33 loads batch-issued ----
        {
            const int nl = tid & 127, ig = tid >> 7;
            const int np = (blk >> 1) * 128 + nl;
            const int k  = np / KJ_STRIDE;
            const int j  = np - k * KJ_STRIDE;     // 0..135 (pad if >128)
            const bool jok = (j <= 128);
            const float* Wkj = W + (size_t)k * 129 + j;
            float wreg[33];
#pragma unroll
            for (int r = 0; r < 33; ++r) {
                int i = ig + r * 4;
                wreg[r] = (i <= 128 && jok) ? Wkj[(size_t)i * 16512] : 0.f;
            }
#pragma unroll
            for (int r = 0; r < 33; ++r) {
                int i = ig + r * 4;
                if (i <= 128) SH[nl * KJ_STRIDE + i] = f2bf(wreg[r]);
            }
        }
        __syncthreads();

        const int bxg = blk & 1;               // bx half (256)
        const int nb  = blk >> 1;              // 0..135
        const int nloc  = wv * 16;             // wave owns 16 n-rows
        const int nglob = nb * 128 + nloc;

        bf16x8 af[4];
#pragma unroll
        for (int is = 0; is < 4; ++is)
            af[is] = *(const bf16x8*)&SH[(nloc + l15) * KJ_STRIDE + is * 32 + 8 * h];
        f32x4 binit;
#pragma unroll
        for (int r = 0; r < 4; ++r)
            binit[r] = bf2f(SH[(nloc + 4 * h + r) * KJ_STRIDE + 128]);   // bias i=128

#pragma unroll 1
        for (int p = 0; p < 4; ++p) {          // 4 passes x 64 bx = 256 bx
            const int bx0 = bxg * 256 + p * 64;
            f32x4 acc[4];
#pragma unroll
            for (int ct = 0; ct < 4; ++ct) acc[ct] = binit;
#pragma unroll
            for (int is = 0; is < 4; ++is)
#pragma unroll
                for (int ct = 0; ct < 4; ++ct) {
                    const float* xs = x + (size_t)(bx0 + ct * 16 + l15) * NI + is * 32 + 8 * h;
                    float4 a = *(const float4*)xs;
                    float4 b = *(const float4*)(xs + 4);
                    ushort8_t u;
                    u[0] = f2bf(a.x); u[1] = f2bf(a.y); u[2] = f2bf(a.z); u[3] = f2bf(a.w);
                    u[4] = f2bf(b.x); u[5] = f2bf(b.y); u[6] = f2bf(b.z); u[7] = f2bf(b.w);
                    bf16x8 xf = __builtin_bit_cast(bf16x8, u);
                    acc[ct] = __builtin_amdgcn_mfma_f32_16x16x32_bf16(af[is], xf, acc[ct], 0, 0, 0);
                }
#pragma unroll
            for (int ct = 0; ct < 4; ++ct) {
                ushort4_t o;
#pragma unroll
                for (int r = 0; r < 4; ++r) o[r] = f2bf(acc[ct][r]);
                *(ushort4_t*)(A2g + (size_t)(bx0 + ct * 16 + l15) * NFLATP + nglob + 4 * h) = o;
            }
        }
    } else if (blk < 336) {
        // ---- y,z prep: 64 blocks x 512 thr x 4 elems = 131072 ----
        int t = (blk - 272) * 512 + tid;
        int base = t * 4;
        int which = base >> 16;                // 0: y, 1: z
        int local = base & 65535;
        const float* s = which ? z : y;
        float4 v = *(const float4*)(s + local);
        ushort4_t o;
        o[0] = f2bf(v.x); o[1] = f2bf(v.y); o[2] = f2bf(v.z); o[3] = f2bf(v.w);
        *(ushort4_t*)(yzbf + base) = o;
    }
    // blocks 336..511: straight to barrier

    // ================= GRID BARRIER =================
    __syncthreads();                            // drains vmcnt(0): all block stores complete
    if (tid == 0) {
        __threadfence();                        // release: wb L2 (cross-XCD visibility)
        atomicAdd(bar, 1u);                     // device-scope
        while (__hip_atomic_load(bar, __ATOMIC_ACQUIRE, __HIP_MEMORY_SCOPE_AGENT) < NBLK)
            __builtin_amdgcn_s_sleep(8);
        __threadfence();                        // acquire: inv stale L2 lines
    }
    __syncthreads();

    // ================= PHASE 2 (r10 stage2 body, bx = blk) =================
    const int bx = blk;
    const int b  = bx >> 8;

    {   // pure vector staging: A2 row layout == LDS layout
        const float4* src = (const float4*)(A2g + (size_t)bx * NFLATP);
        float4* dst = (float4*)SH;
        for (int t = tid; t < NFLATP / 8; t += 512) dst[t] = src[t];
    }
    __syncthreads();

    const unsigned short* yb = yzbf + b * LL * NI;
    const unsigned short* zb = yzbf + 65536 + b * LL * NI;
    const int y0 = wv * 32;                // wave owns 32 of 256 y in phase A

    // ---- Phase A: P'[k,y] = sum_j A2[k,j]*y[y,j] + A2[k,128] ----
    f32x4 accP[8][2];                      // [k-tile][y-tile]; lane: y=l15(col), k=4h+r(row)
#pragma unroll
    for (int kt = 0; kt < 8; ++kt)
#pragma unroll
        for (int r = 0; r < 4; ++r) {
            float bias = bf2f(SH[(kt * 16 + 4 * h + r) * KJ_STRIDE + 128]);
            accP[kt][0][r] = bias; accP[kt][1][r] = bias;
        }
#pragma unroll
    for (int js = 0; js < 4; ++js) {
        bf16x8 yf[2];
#pragma unroll
        for (int yt = 0; yt < 2; ++yt)
            yf[yt] = *(const bf16x8*)(yb + (y0 + yt * 16 + l15) * NI + js * 32 + 8 * h);
#pragma unroll
        for (int kt = 0; kt < 8; ++kt) {
            bf16x8 af2 = *(const bf16x8*)&SH[(kt * 16 + l15) * KJ_STRIDE + js * 32 + 8 * h];
            accP[kt][0] = __builtin_amdgcn_mfma_f32_16x16x32_bf16(af2, yf[0], accP[kt][0], 0, 0, 0);
            accP[kt][1] = __builtin_amdgcn_mfma_f32_16x16x32_bf16(af2, yf[1], accP[kt][1], 0, 0, 0);
        }
    }
    __syncthreads();   // all waves done reading A2 region

    // ---- P' -> LDS [y][P_STRIDE] bf16 ----
#pragma unroll
    for (int kt = 0; kt < 8; ++kt)
#pragma unroll
        for (int yt = 0; yt < 2; ++yt) {
            unsigned lo = (unsigned)f2bf(accP[kt][yt][0]) | ((unsigned)f2bf(accP[kt][yt][1]) << 16);
            unsigned hi = (unsigned)f2bf(accP[kt][yt][2]) | ((unsigned)f2bf(accP[kt][yt][3]) << 16);
            uint2 v; v.x = lo; v.y = hi;
            *(uint2*)&SH[(y0 + yt * 16 + l15) * P_STRIDE + kt * 16 + 4 * h] = v;
        }

    // z fragments: wave owns 64 z-rows, loaded once (overlaps ds_writes above)
    const int zg = wv & 3, yh = wv >> 2;
    const int z0 = zg * 64;
    short4_t zf[4][8];
#pragma unroll
    for (int zt = 0; zt < 4; ++zt)
#pragma unroll
        for (int kt = 0; kt < 8; ++kt)
            zf[zt][kt] = *(const short4_t*)(zb + (z0 + zt * 16 + l15) * NI + kt * 16 + 4 * h);

    __syncthreads();   // P' visible

    // ---- Phase B: S[y,z] = sum_k z[z,k]*P'[k,y]; wave: 64 z x 128 y ----
    float* outb = out + (size_t)bx * (LL * LL);
#pragma unroll 1
    for (int yti = 0; yti < 8; ++yti) {
        const int yy = yh * 128 + yti * 16 + l15;    // this lane's y (col)
        f32x4 acc2[4];
#pragma unroll
        for (int zt = 0; zt < 4; ++zt) { acc2[zt][0] = 0.f; acc2[zt][1] = 0.f; acc2[zt][2] = 0.f; acc2[zt][3] = 0.f; }
#pragma unroll
        for (int kt = 0; kt < 8; ++kt) {
            short4_t pB = *(const short4_t*)&SH[yy * P_STRIDE + kt * 16 + 4 * h];
#pragma unroll
            for (int zt = 0; zt < 4; ++zt)
                acc2[zt] = __builtin_amdgcn_mfma_f32_16x16x16bf16_1k(zf[zt][kt], pB, acc2[zt], 0, 0, 0);
        }
#pragma unroll
        for (int zt = 0; zt < 4; ++zt)
            *(f32x4*)(outb + (size_t)yy * LL + z0 + zt * 16 + 4 * h) = acc2[zt];
    }
}

extern "C" void kernel_launch(void* const* d_in, const int* in_sizes, int n_in,
                              void* d_out, int out_size, void* d_ws, size_t ws_size,
                              hipStream_t stream) {
    const float* x = (const float*)d_in[0];
    const float* y = (const float*)d_in[1];
    const float* z = (const float*)d_in[2];
    const float* W = (const float*)d_in[3];   // [129][128][129][1] = [129][16512]
    float* out = (float*)d_out;

    unsigned* bar = (unsigned*)d_ws;                          // 256 B region
    unsigned short* yzbf = (unsigned short*)((char*)d_ws + 256);  // y:65536 + z:65536
    unsigned short* A2g  = yzbf + 131072;                     // 512*17408 (~17.8 MB)

    hipMemsetAsync(bar, 0, 256, stream);      // reset barrier (capture-legal stream op)
    fused_kernel<<<NBLK, 512, 0, stream>>>(W, x, y, z, yzbf, A2g, out, bar);
}

// Round 12
// 169.025 us; speedup vs baseline: 1.5383x; 1.5383x over previous
//
#include <hip/hip_runtime.h>

// TriAffine: S[b,x,y,z] = sum_{i,k,j} xb[b,x,i] z[b,z,k] W[i,k,j] yb[b,y,j]
// B=2, L=256, N_IN=128. Output [2,256,256,256] f32 (134 MB).
//
// SINGLE persistent kernel (512 blocks x 512 thr, exactly 2/CU co-resident).
// r11 post-mortem: acquire-load spin invalidated L2 per iteration -> 190us of
// cache-thrash (MfmaUtil 3.5%, HBM 0.6 TB/s, traffic nominal). r12 fix: spin
// via device-scope atomic RMW probe (atomicAdd(bar,0): serviced at coherence
// point, NO L2 invalidate), fences hoisted outside the loop.
//
//  phase1: blocks 0..271: W tile -> LDS (33-reg batch loads) + flat GEMM
//          A2[bx][n'] (x direct from global f32, inline cvt; n'=k*136+j).
//          blocks 272..335: y,z f32 -> bf16. Others straight to barrier.
//  phase2: stage2 body (r8-r11 baseline), bx = blockIdx.x.

typedef __bf16 bf16x8 __attribute__((ext_vector_type(8)));
typedef unsigned short ushort8_t __attribute__((ext_vector_type(8)));
typedef short short4_t __attribute__((ext_vector_type(4)));
typedef float f32x4 __attribute__((ext_vector_type(4)));
typedef unsigned short ushort4_t __attribute__((ext_vector_type(4)));

#define LL 256
#define NI 128
#define NFLATP 17408           // 128 * 136 (padded (k,j) axis)
#define KJ_STRIDE 136          // j-stride within A2 row / LDS
#define P_STRIDE 132           // P' LDS k-stride (264B)
#define NBLK 512

__device__ __forceinline__ unsigned short f2bf(float f) {
    unsigned u = __builtin_bit_cast(unsigned, f);
    u += 0x7FFFu + ((u >> 16) & 1u);   // RNE
    return (unsigned short)(u >> 16);
}
__device__ __forceinline__ float bf2f(unsigned short h) {
    return __builtin_bit_cast(float, (unsigned)h << 16);
}

__global__ __launch_bounds__(512, 4) void fused_kernel(const float* __restrict__ W,
                                                       const float* __restrict__ x,
                                                       const float* __restrict__ y,
                                                       const float* __restrict__ z,
                                                       unsigned short* __restrict__ yzbf,
                                                       unsigned short* __restrict__ A2g,
                                                       float* __restrict__ out,
                                                       unsigned* bar) {
    const int blk = blockIdx.x, tid = threadIdx.x;
    __shared__ __align__(16) unsigned short SH[LL * P_STRIDE];   // 67584 B (T aliases in phase1)

    const int wv = tid >> 6, lane = tid & 63;
    const int l15 = lane & 15, h = lane >> 4;

    // ================= PHASE 1 =================
    if (blk < 272) {
        // ---- W stage: SH as T[128][136]; all 33 loads batch-issued ----
        {
            const int nl = tid & 127, ig = tid >> 7;
            const int np = (blk >> 1) * 128 + nl;
            const int k  = np / KJ_STRIDE;
            const int j  = np - k * KJ_STRIDE;     // 0..135 (pad if >128)
            const bool jok = (j <= 128);
            const float* Wkj = W + (size_t)k * 129 + j;
            float wreg[33];
#pragma unroll
            for (int r = 0; r < 33; ++r) {
                int i = ig + r * 4;
                wreg[r] = (i <= 128 && jok) ? Wkj[(size_t)i * 16512] : 0.f;
            }
#pragma unroll
            for (int r = 0; r < 33; ++r) {
                int i = ig + r * 4;
                if (i <= 128) SH[nl * KJ_STRIDE + i] = f2bf(wreg[r]);
            }
        }
        __syncthreads();

        const int bxg = blk & 1;               // bx half (256)
        const int nb  = blk >> 1;              // 0..135
        const int nloc  = wv * 16;             // wave owns 16 n-rows
        const int nglob = nb * 128 + nloc;

        bf16x8 af[4];
#pragma unroll
        for (int is = 0; is < 4; ++is)
            af[is] = *(const bf16x8*)&SH[(nloc + l15) * KJ_STRIDE + is * 32 + 8 * h];
        f32x4 binit;
#pragma unroll
        for (int r = 0; r < 4; ++r)
            binit[r] = bf2f(SH[(nloc + 4 * h + r) * KJ_STRIDE + 128]);   // bias i=128

#pragma unroll 1
        for (int p = 0; p < 4; ++p) {          // 4 passes x 64 bx = 256 bx
            const int bx0 = bxg * 256 + p * 64;
            f32x4 acc[4];
#pragma unroll
            for (int ct = 0; ct < 4; ++ct) acc[ct] = binit;
#pragma unroll
            for (int is = 0; is < 4; ++is)
#pragma unroll
                for (int ct = 0; ct < 4; ++ct) {
                    const float* xs = x + (size_t)(bx0 + ct * 16 + l15) * NI + is * 32 + 8 * h;
                    float4 a = *(const float4*)xs;
                    float4 b = *(const float4*)(xs + 4);
                    ushort8_t u;
                    u[0] = f2bf(a.x); u[1] = f2bf(a.y); u[2] = f2bf(a.z); u[3] = f2bf(a.w);
                    u[4] = f2bf(b.x); u[5] = f2bf(b.y); u[6] = f2bf(b.z); u[7] = f2bf(b.w);
                    bf16x8 xf = __builtin_bit_cast(bf16x8, u);
                    acc[ct] = __builtin_amdgcn_mfma_f32_16x16x32_bf16(af[is], xf, acc[ct], 0, 0, 0);
                }
#pragma unroll
            for (int ct = 0; ct < 4; ++ct) {
                ushort4_t o;
#pragma unroll
                for (int r = 0; r < 4; ++r) o[r] = f2bf(acc[ct][r]);
                *(ushort4_t*)(A2g + (size_t)(bx0 + ct * 16 + l15) * NFLATP + nglob + 4 * h) = o;
            }
        }
    } else if (blk < 336) {
        // ---- y,z prep: 64 blocks x 512 thr x 4 elems = 131072 ----
        int t = (blk - 272) * 512 + tid;
        int base = t * 4;
        int which = base >> 16;                // 0: y, 1: z
        int local = base & 65535;
        const float* s = which ? z : y;
        float4 v = *(const float4*)(s + local);
        ushort4_t o;
        o[0] = f2bf(v.x); o[1] = f2bf(v.y); o[2] = f2bf(v.z); o[3] = f2bf(v.w);
        *(ushort4_t*)(yzbf + base) = o;
    }
    // blocks 336..511: straight to barrier

    // ================= GRID BARRIER (RMW-probe spin, fences outside loop) =================
    __syncthreads();                            // all block stores issued
    if (tid == 0) {
        __threadfence();                        // release: wb L2 once
        atomicAdd(bar, 1u);                     // device-scope arrive
        while (atomicAdd(bar, 0u) < NBLK)       // RMW probe at coherence point: no L2 inv
            __builtin_amdgcn_s_sleep(32);
        __threadfence();                        // acquire once
    }
    __syncthreads();

    // ================= PHASE 2 (stage2 body, bx = blk) =================
    const int bx = blk;
    const int b  = bx >> 8;

    {   // pure vector staging: A2 row layout == LDS layout
        const float4* src = (const float4*)(A2g + (size_t)bx * NFLATP);
        float4* dst = (float4*)SH;
        for (int t = tid; t < NFLATP / 8; t += 512) dst[t] = src[t];
    }
    __syncthreads();

    const unsigned short* yb = yzbf + b * LL * NI;
    const unsigned short* zb = yzbf + 65536 + b * LL * NI;
    const int y0 = wv * 32;                // wave owns 32 of 256 y in phase A

    // ---- Phase A: P'[k,y] = sum_j A2[k,j]*y[y,j] + A2[k,128] ----
    f32x4 accP[8][2];                      // [k-tile][y-tile]; lane: y=l15(col), k=4h+r(row)
#pragma unroll
    for (int kt = 0; kt < 8; ++kt)
#pragma unroll
        for (int r = 0; r < 4; ++r) {
            float bias = bf2f(SH[(kt * 16 + 4 * h + r) * KJ_STRIDE + 128]);
            accP[kt][0][r] = bias; accP[kt][1][r] = bias;
        }
#pragma unroll
    for (int js = 0; js < 4; ++js) {
        bf16x8 yf[2];
#pragma unroll
        for (int yt = 0; yt < 2; ++yt)
            yf[yt] = *(const bf16x8*)(yb + (y0 + yt * 16 + l15) * NI + js * 32 + 8 * h);
#pragma unroll
        for (int kt = 0; kt < 8; ++kt) {
            bf16x8 af2 = *(const bf16x8*)&SH[(kt * 16 + l15) * KJ_STRIDE + js * 32 + 8 * h];
            accP[kt][0] = __builtin_amdgcn_mfma_f32_16x16x32_bf16(af2, yf[0], accP[kt][0], 0, 0, 0);
            accP[kt][1] = __builtin_amdgcn_mfma_f32_16x16x32_bf16(af2, yf[1], accP[kt][1], 0, 0, 0);
        }
    }
    __syncthreads();   // all waves done reading A2 region

    // ---- P' -> LDS [y][P_STRIDE] bf16 ----
#pragma unroll
    for (int kt = 0; kt < 8; ++kt)
#pragma unroll
        for (int yt = 0; yt < 2; ++yt) {
            unsigned lo = (unsigned)f2bf(accP[kt][yt][0]) | ((unsigned)f2bf(accP[kt][yt][1]) << 16);
            unsigned hi = (unsigned)f2bf(accP[kt][yt][2]) | ((unsigned)f2bf(accP[kt][yt][3]) << 16);
            uint2 v; v.x = lo; v.y = hi;
            *(uint2*)&SH[(y0 + yt * 16 + l15) * P_STRIDE + kt * 16 + 4 * h] = v;
        }

    // z fragments: wave owns 64 z-rows, loaded once (overlaps ds_writes above)
    const int zg = wv & 3, yh = wv >> 2;
    const int z0 = zg * 64;
    short4_t zf[4][8];
#pragma unroll
    for (int zt = 0; zt < 4; ++zt)
#pragma unroll
        for (int kt = 0; kt < 8; ++kt)
            zf[zt][kt] = *(const short4_t*)(zb + (z0 + zt * 16 + l15) * NI + kt * 16 + 4 * h);

    __syncthreads();   // P' visible

    // ---- Phase B: S[y,z] = sum_k z[z,k]*P'[k,y]; wave: 64 z x 128 y ----
    float* outb = out + (size_t)bx * (LL * LL);
#pragma unroll 1
    for (int yti = 0; yti < 8; ++yti) {
        const int yy = yh * 128 + yti * 16 + l15;    // this lane's y (col)
        f32x4 acc2[4];
#pragma unroll
        for (int zt = 0; zt < 4; ++zt) { acc2[zt][0] = 0.f; acc2[zt][1] = 0.f; acc2[zt][2] = 0.f; acc2[zt][3] = 0.f; }
#pragma unroll
        for (int kt = 0; kt < 8; ++kt) {
            short4_t pB = *(const short4_t*)&SH[yy * P_STRIDE + kt * 16 + 4 * h];
#pragma unroll
            for (int zt = 0; zt < 4; ++zt)
                acc2[zt] = __builtin_amdgcn_mfma_f32_16x16x16bf16_1k(zf[zt][kt], pB, acc2[zt], 0, 0, 0);
        }
#pragma unroll
        for (int zt = 0; zt < 4; ++zt)
            *(f32x4*)(outb + (size_t)yy * LL + z0 + zt * 16 + 4 * h) = acc2[zt];
    }
}

extern "C" void kernel_launch(void* const* d_in, const int* in_sizes, int n_in,
                              void* d_out, int out_size, void* d_ws, size_t ws_size,
                              hipStream_t stream) {
    const float* x = (const float*)d_in[0];
    const float* y = (const float*)d_in[1];
    const float* z = (const float*)d_in[2];
    const float* W = (const float*)d_in[3];   // [129][128][129][1] = [129][16512]
    float* out = (float*)d_out;

    unsigned* bar = (unsigned*)d_ws;                          // 256 B region
    unsigned short* yzbf = (unsigned short*)((char*)d_ws + 256);  // y:65536 + z:65536
    unsigned short* A2g  = yzbf + 131072;                     // 512*17408 (~17.8 MB)

    hipMemsetAsync(bar, 0, 256, stream);      // reset barrier (capture-legal stream op)
    fused_kernel<<<NBLK, 512, 0, stream>>>(W, x, y, z, yzbf, A2g, out, bar);
}

// Round 13
// 111.683 us; speedup vs baseline: 2.3282x; 1.5134x over previous
//
#include <hip/hip_runtime.h>

// TriAffine: S[b,x,y,z] = sum_{i,k,j} xb[b,x,i] z[b,z,k] W[i,k,j] yb[b,y,j]
// B=2, L=256, N_IN=128. Output [2,256,256,256] f32 (134 MB).
//
// Two kernels (r12 grid-barrier experiment: dead end, 100us spin serialization).
//  stage1 : r12's lean phase-1: W tile -> LDS T (34.8 KB ONLY -> 4 blocks/CU,
//           all 336 blocks one round; r10's version had +67KB XB -> 1/CU ->
//           2 serial rounds = the hidden ~14us). x read direct from global f32
//           with inline cvt. Blocks 272..335: y,z f32 -> bf16.
//  stage2 : byte-identical r8-r10 baseline (37.4us measured via r9 3x probe).

typedef __bf16 bf16x8 __attribute__((ext_vector_type(8)));
typedef unsigned short ushort8_t __attribute__((ext_vector_type(8)));
typedef short short4_t __attribute__((ext_vector_type(4)));
typedef float f32x4 __attribute__((ext_vector_type(4)));
typedef unsigned short ushort4_t __attribute__((ext_vector_type(4)));

#define LL 256
#define NI 128
#define NFLATP 17408           // 128 * 136 (padded (k,j) axis)
#define KJ_STRIDE 136          // j-stride within A2 row / LDS
#define P_STRIDE 132           // P' LDS k-stride (264B)

__device__ __forceinline__ unsigned short f2bf(float f) {
    unsigned u = __builtin_bit_cast(unsigned, f);
    u += 0x7FFFu + ((u >> 16) & 1u);   // RNE
    return (unsigned short)(u >> 16);
}
__device__ __forceinline__ float bf2f(unsigned short h) {
    return __builtin_bit_cast(float, (unsigned)h << 16);
}

// ---------------- stage1: W-stage (LDS) + flat GEMM + yz-prep ----------------
// blocks 0..271: (bxg = blk&1, nb = blk>>1); 512 thr (8 waves), 34.8 KB LDS.
// blocks 272..335: y,z f32 -> bf16.
__global__ __launch_bounds__(512) void stage1_kernel(const float* __restrict__ W,
                                                     const float* __restrict__ x,
                                                     const float* __restrict__ y,
                                                     const float* __restrict__ z,
                                                     unsigned short* __restrict__ yzbf,
                                                     unsigned short* __restrict__ A2g) {
    const int blk = blockIdx.x, tid = threadIdx.x;

    if (blk >= 272) {           // ---- yz prep ----
        int t = (blk - 272) * 512 + tid;
        int base = t * 4;
        int which = base >> 16;                // 0: y, 1: z
        int local = base & 65535;
        const float* s = which ? z : y;
        float4 v = *(const float4*)(s + local);
        ushort4_t o;
        o[0] = f2bf(v.x); o[1] = f2bf(v.y); o[2] = f2bf(v.z); o[3] = f2bf(v.w);
        *(ushort4_t*)(yzbf + base) = o;
        return;
    }

    __shared__ unsigned short T[128 * KJ_STRIDE];   // 34816 B

    const int wv = tid >> 6, lane = tid & 63;
    const int l15 = lane & 15, h = lane >> 4;

    {   // ---- W stage: T[nl][i]; all 33 loads batch-issued ----
        const int nl = tid & 127, ig = tid >> 7;
        const int np = (blk >> 1) * 128 + nl;
        const int k  = np / KJ_STRIDE;
        const int j  = np - k * KJ_STRIDE;     // 0..135 (pad if >128)
        const bool jok = (j <= 128);
        const float* Wkj = W + (size_t)k * 129 + j;
        float wreg[33];
#pragma unroll
        for (int r = 0; r < 33; ++r) {
            int i = ig + r * 4;
            wreg[r] = (i <= 128 && jok) ? Wkj[(size_t)i * 16512] : 0.f;
        }
#pragma unroll
        for (int r = 0; r < 33; ++r) {
            int i = ig + r * 4;
            if (i <= 128) T[nl * KJ_STRIDE + i] = f2bf(wreg[r]);
        }
    }
    __syncthreads();

    const int bxg = blk & 1;               // bx half (256)
    const int nb  = blk >> 1;              // 0..135
    const int nloc  = wv * 16;             // wave owns 16 n-rows
    const int nglob = nb * 128 + nloc;

    bf16x8 af[4];
#pragma unroll
    for (int is = 0; is < 4; ++is)
        af[is] = *(const bf16x8*)&T[(nloc + l15) * KJ_STRIDE + is * 32 + 8 * h];
    f32x4 binit;
#pragma unroll
    for (int r = 0; r < 4; ++r)
        binit[r] = bf2f(T[(nloc + 4 * h + r) * KJ_STRIDE + 128]);   // bias i=128

#pragma unroll 1
    for (int p = 0; p < 4; ++p) {          // 4 passes x 64 bx = 256 bx
        const int bx0 = bxg * 256 + p * 64;
        f32x4 acc[4];
#pragma unroll
        for (int ct = 0; ct < 4; ++ct) acc[ct] = binit;
#pragma unroll
        for (int is = 0; is < 4; ++is)
#pragma unroll
            for (int ct = 0; ct < 4; ++ct) {
                const float* xs = x + (size_t)(bx0 + ct * 16 + l15) * NI + is * 32 + 8 * h;
                float4 a = *(const float4*)xs;
                float4 b = *(const float4*)(xs + 4);
                ushort8_t u;
                u[0] = f2bf(a.x); u[1] = f2bf(a.y); u[2] = f2bf(a.z); u[3] = f2bf(a.w);
                u[4] = f2bf(b.x); u[5] = f2bf(b.y); u[6] = f2bf(b.z); u[7] = f2bf(b.w);
                bf16x8 xf = __builtin_bit_cast(bf16x8, u);
                acc[ct] = __builtin_amdgcn_mfma_f32_16x16x32_bf16(af[is], xf, acc[ct], 0, 0, 0);
            }
#pragma unroll
        for (int ct = 0; ct < 4; ++ct) {
            ushort4_t o;
#pragma unroll
            for (int r = 0; r < 4; ++r) o[r] = f2bf(acc[ct][r]);
            *(ushort4_t*)(A2g + (size_t)(bx0 + ct * 16 + l15) * NFLATP + nglob + 4 * h) = o;
        }
    }
}

// ---------------- stage2: per (b,x) block -> S[y,z] 256x256 (baseline) ----------------
__global__ __launch_bounds__(512, 4) void stage2_kernel(const unsigned short* __restrict__ ybf,
                                                        const unsigned short* __restrict__ zbf,
                                                        const unsigned short* __restrict__ A2g,
                                                        float* __restrict__ out) {
    const int bx  = blockIdx.x;            // b*256 + x
    const int b   = bx >> 8;
    const int tid = threadIdx.x;
    const int wv = tid >> 6, lane = tid & 63;
    const int l15 = lane & 15, h = lane >> 4;

    __shared__ __align__(16) unsigned short SH[LL * P_STRIDE];   // 67584 B

    {   // pure vector staging: A2 row layout == LDS layout
        const float4* src = (const float4*)(A2g + (size_t)bx * NFLATP);
        float4* dst = (float4*)SH;
        for (int t = tid; t < NFLATP / 8; t += 512) dst[t] = src[t];
    }
    __syncthreads();

    const unsigned short* yb = ybf + b * LL * NI;
    const unsigned short* zb = zbf + b * LL * NI;
    const int y0 = wv * 32;                // wave owns 32 of 256 y in phase A

    // ---- Phase A: P'[k,y] = sum_j A2[k,j]*y[y,j] + A2[k,128] ----
    f32x4 accP[8][2];                      // [k-tile][y-tile]; lane: y=l15(col), k=4h+r(row)
#pragma unroll
    for (int kt = 0; kt < 8; ++kt)
#pragma unroll
        for (int r = 0; r < 4; ++r) {
            float bias = bf2f(SH[(kt * 16 + 4 * h + r) * KJ_STRIDE + 128]);
            accP[kt][0][r] = bias; accP[kt][1][r] = bias;
        }
#pragma unroll
    for (int js = 0; js < 4; ++js) {
        bf16x8 yf[2];
#pragma unroll
        for (int yt = 0; yt < 2; ++yt)
            yf[yt] = *(const bf16x8*)(yb + (y0 + yt * 16 + l15) * NI + js * 32 + 8 * h);
#pragma unroll
        for (int kt = 0; kt < 8; ++kt) {
            bf16x8 af2 = *(const bf16x8*)&SH[(kt * 16 + l15) * KJ_STRIDE + js * 32 + 8 * h];
            accP[kt][0] = __builtin_amdgcn_mfma_f32_16x16x32_bf16(af2, yf[0], accP[kt][0], 0, 0, 0);
            accP[kt][1] = __builtin_amdgcn_mfma_f32_16x16x32_bf16(af2, yf[1], accP[kt][1], 0, 0, 0);
        }
    }
    __syncthreads();   // all waves done reading A2 region

    // ---- P' -> LDS [y][P_STRIDE] bf16 ----
#pragma unroll
    for (int kt = 0; kt < 8; ++kt)
#pragma unroll
        for (int yt = 0; yt < 2; ++yt) {
            unsigned lo = (unsigned)f2bf(accP[kt][yt][0]) | ((unsigned)f2bf(accP[kt][yt][1]) << 16);
            unsigned hi = (unsigned)f2bf(accP[kt][yt][2]) | ((unsigned)f2bf(accP[kt][yt][3]) << 16);
            uint2 v; v.x = lo; v.y = hi;
            *(uint2*)&SH[(y0 + yt * 16 + l15) * P_STRIDE + kt * 16 + 4 * h] = v;
        }

    // z fragments: wave owns 64 z-rows, loaded once (overlaps ds_writes above)
    const int zg = wv & 3, yh = wv >> 2;
    const int z0 = zg * 64;
    short4_t zf[4][8];
#pragma unroll
    for (int zt = 0; zt < 4; ++zt)
#pragma unroll
        for (int kt = 0; kt < 8; ++kt)
            zf[zt][kt] = *(const short4_t*)(zb + (z0 + zt * 16 + l15) * NI + kt * 16 + 4 * h);

    __syncthreads();   // P' visible

    // ---- Phase B: S[y,z] = sum_k z[z,k]*P'[k,y]; wave: 64 z x 128 y ----
    float* outb = out + (size_t)bx * (LL * LL);
#pragma unroll 1
    for (int yti = 0; yti < 8; ++yti) {
        const int yy = yh * 128 + yti * 16 + l15;    // this lane's y (col)
        f32x4 acc2[4];
#pragma unroll
        for (int zt = 0; zt < 4; ++zt) { acc2[zt][0] = 0.f; acc2[zt][1] = 0.f; acc2[zt][2] = 0.f; acc2[zt][3] = 0.f; }
#pragma unroll
        for (int kt = 0; kt < 8; ++kt) {
            short4_t pB = *(const short4_t*)&SH[yy * P_STRIDE + kt * 16 + 4 * h];
#pragma unroll
            for (int zt = 0; zt < 4; ++zt)
                acc2[zt] = __builtin_amdgcn_mfma_f32_16x16x16bf16_1k(zf[zt][kt], pB, acc2[zt], 0, 0, 0);
        }
#pragma unroll
        for (int zt = 0; zt < 4; ++zt)
            *(f32x4*)(outb + (size_t)yy * LL + z0 + zt * 16 + 4 * h) = acc2[zt];
    }
}

extern "C" void kernel_launch(void* const* d_in, const int* in_sizes, int n_in,
                              void* d_out, int out_size, void* d_ws, size_t ws_size,
                              hipStream_t stream) {
    const float* x = (const float*)d_in[0];
    const float* y = (const float*)d_in[1];
    const float* z = (const float*)d_in[2];
    const float* W = (const float*)d_in[3];   // [129][128][129][1] = [129][16512]
    float* out = (float*)d_out;

    unsigned short* yzbf = (unsigned short*)d_ws;            // y:65536 + z:65536
    unsigned short* A2g  = yzbf + 131072;                    // 512*17408 (~17.8 MB)

    stage1_kernel<<<336, 512, 0, stream>>>(W, x, y, z, yzbf, A2g);
    stage2_kernel<<<512, 512, 0, stream>>>(yzbf, yzbf + 65536, A2g, out);
}

// Round 14
// 67.306 us; speedup vs baseline: 3.8632x; 1.6593x over previous
//
#include <hip/hip_runtime.h>

// TriAffine: S[b,x,y,z] = sum_{i,k,j} xb[b,x,i] z[b,z,k] W[i,k,j] yb[b,y,j]
// B=2, L=256, N_IN=128. Output [2,256,256,256] f32 (134 MB).
//
// r13 post-mortem: x-from-global-in-inner-loop = scattered loads + 8x redundant
// cvt VALU -> stage1 74us. Revert to r10's stage-x-once-in-LDS, but with XB
// halved (two 128-bx sub-passes reusing one 33.8KB buffer): T+XB = 68.6KB ->
// 2 blocks/CU -> all 336 blocks co-resident in ONE round (r10 ran 2 rounds at
// 1/CU = its hidden ~14us).
//  stage1 : W tile -> LDS T (33-reg batch, coalesced); per sp in {0,1}:
//           stage XB[128][132] (coalesced float4, cvt once), GEMM 16n x 128bx
//           per wave, store A2[bx][n'] (n' = k*136+j).
//           Blocks 272..335: y,z f32 -> bf16.
//  stage2 : byte-identical r8-r10 baseline (37.4us measured via r9 3x probe).

typedef __bf16 bf16x8 __attribute__((ext_vector_type(8)));
typedef short short4_t __attribute__((ext_vector_type(4)));
typedef float f32x4 __attribute__((ext_vector_type(4)));
typedef unsigned short ushort4_t __attribute__((ext_vector_type(4)));

#define LL 256
#define NI 128
#define NFLATP 17408           // 128 * 136 (padded (k,j) axis)
#define KJ_STRIDE 136          // j-stride within A2 row / LDS
#define XB_STRIDE 132          // x LDS i-stride
#define P_STRIDE 132           // P' LDS k-stride (264B)

__device__ __forceinline__ unsigned short f2bf(float f) {
    unsigned u = __builtin_bit_cast(unsigned, f);
    u += 0x7FFFu + ((u >> 16) & 1u);   // RNE
    return (unsigned short)(u >> 16);
}
__device__ __forceinline__ float bf2f(unsigned short h) {
    return __builtin_bit_cast(float, (unsigned)h << 16);
}

// ---------------- stage1: W-stage + two-sub-pass GEMM + yz-prep ----------------
// blocks 0..271: (bxg = blk&1, nb = blk>>1); 512 thr (8 waves), 68.6 KB LDS.
// blocks 272..335: y,z f32 -> bf16.
__global__ __launch_bounds__(512, 4) void stage1_kernel(const float* __restrict__ W,
                                                        const float* __restrict__ x,
                                                        const float* __restrict__ y,
                                                        const float* __restrict__ z,
                                                        unsigned short* __restrict__ yzbf,
                                                        unsigned short* __restrict__ A2g) {
    const int blk = blockIdx.x, tid = threadIdx.x;

    if (blk >= 272) {           // ---- yz prep: 64 blocks x 512 thr x 4 elems ----
        int t = (blk - 272) * 512 + tid;
        int base = t * 4;
        int which = base >> 16;                // 0: y, 1: z
        int local = base & 65535;
        const float* s = which ? z : y;
        float4 v = *(const float4*)(s + local);
        ushort4_t o;
        o[0] = f2bf(v.x); o[1] = f2bf(v.y); o[2] = f2bf(v.z); o[3] = f2bf(v.w);
        *(ushort4_t*)(yzbf + base) = o;
        return;
    }

    __shared__ unsigned short T[128 * KJ_STRIDE];    // 34816 B: [n_local][i]
    __shared__ unsigned short XB[128 * XB_STRIDE];   // 33792 B: [bx_local][i]

    const int wv = tid >> 6, lane = tid & 63;
    const int l15 = lane & 15, h = lane >> 4;

    {   // ---- W stage: T[nl][i]; all 33 loads batch-issued, coalesced ----
        const int nl = tid & 127, ig = tid >> 7;
        const int np = (blk >> 1) * 128 + nl;
        const int k  = np / KJ_STRIDE;
        const int j  = np - k * KJ_STRIDE;     // 0..135 (pad if >128)
        const bool jok = (j <= 128);
        const float* Wkj = W + (size_t)k * 129 + j;
        float wreg[33];
#pragma unroll
        for (int r = 0; r < 33; ++r) {
            int i = ig + r * 4;
            wreg[r] = (i <= 128 && jok) ? Wkj[(size_t)i * 16512] : 0.f;
        }
#pragma unroll
        for (int r = 0; r < 33; ++r) {
            int i = ig + r * 4;
            if (i <= 128) T[nl * KJ_STRIDE + i] = f2bf(wreg[r]);
        }
    }
    __syncthreads();

    const int bxg = blk & 1;               // bx half (256)
    const int nb  = blk >> 1;              // 0..135
    const int nloc  = wv * 16;             // wave owns 16 n-rows
    const int nglob = nb * 128 + nloc;

    bf16x8 af[4];
#pragma unroll
    for (int is = 0; is < 4; ++is)
        af[is] = *(const bf16x8*)&T[(nloc + l15) * KJ_STRIDE + is * 32 + 8 * h];
    f32x4 binit;
#pragma unroll
    for (int r = 0; r < 4; ++r)
        binit[r] = bf2f(T[(nloc + 4 * h + r) * KJ_STRIDE + 128]);   // bias i=128

#pragma unroll 1
    for (int sp = 0; sp < 2; ++sp) {       // two 128-bx sub-passes, XB reused
        if (sp) __syncthreads();           // prior sub-pass XB reads complete
        const int bx0 = bxg * 256 + sp * 128;

        {   // ---- stage XB[128][132]: coalesced float4 reads, cvt once ----
            const float* xsrc = x + (size_t)bx0 * NI;
#pragma unroll
            for (int c = 0; c < 8; ++c) {
                int idx = c * 512 + tid;           // float4 idx 0..4095
                float4 v = *(const float4*)(xsrc + (size_t)idx * 4);
                int row = idx >> 5, col = (idx & 31) * 4;
                ushort4_t o;
                o[0] = f2bf(v.x); o[1] = f2bf(v.y); o[2] = f2bf(v.z); o[3] = f2bf(v.w);
                *(ushort4_t*)&XB[row * XB_STRIDE + col] = o;
            }
        }
        __syncthreads();

        f32x4 acc[8];
#pragma unroll
        for (int ct = 0; ct < 8; ++ct) acc[ct] = binit;
#pragma unroll
        for (int is = 0; is < 4; ++is)
#pragma unroll
            for (int ct = 0; ct < 8; ++ct) {
                bf16x8 xf = *(const bf16x8*)&XB[(ct * 16 + l15) * XB_STRIDE + is * 32 + 8 * h];
                acc[ct] = __builtin_amdgcn_mfma_f32_16x16x32_bf16(af[is], xf, acc[ct], 0, 0, 0);
            }
#pragma unroll
        for (int ct = 0; ct < 8; ++ct) {
            ushort4_t o;
#pragma unroll
            for (int r = 0; r < 4; ++r) o[r] = f2bf(acc[ct][r]);
            *(ushort4_t*)(A2g + (size_t)(bx0 + ct * 16 + l15) * NFLATP + nglob + 4 * h) = o;
        }
    }
}

// ---------------- stage2: per (b,x) block -> S[y,z] 256x256 (baseline) ----------------
__global__ __launch_bounds__(512, 4) void stage2_kernel(const unsigned short* __restrict__ ybf,
                                                        const unsigned short* __restrict__ zbf,
                                                        const unsigned short* __restrict__ A2g,
                                                        float* __restrict__ out) {
    const int bx  = blockIdx.x;            // b*256 + x
    const int b   = bx >> 8;
    const int tid = threadIdx.x;
    const int wv = tid >> 6, lane = tid & 63;
    const int l15 = lane & 15, h = lane >> 4;

    __shared__ __align__(16) unsigned short SH[LL * P_STRIDE];   // 67584 B

    {   // pure vector staging: A2 row layout == LDS layout
        const float4* src = (const float4*)(A2g + (size_t)bx * NFLATP);
        float4* dst = (float4*)SH;
        for (int t = tid; t < NFLATP / 8; t += 512) dst[t] = src[t];
    }
    __syncthreads();

    const unsigned short* yb = ybf + b * LL * NI;
    const unsigned short* zb = zbf + b * LL * NI;
    const int y0 = wv * 32;                // wave owns 32 of 256 y in phase A

    // ---- Phase A: P'[k,y] = sum_j A2[k,j]*y[y,j] + A2[k,128] ----
    f32x4 accP[8][2];                      // [k-tile][y-tile]; lane: y=l15(col), k=4h+r(row)
#pragma unroll
    for (int kt = 0; kt < 8; ++kt)
#pragma unroll
        for (int r = 0; r < 4; ++r) {
            float bias = bf2f(SH[(kt * 16 + 4 * h + r) * KJ_STRIDE + 128]);
            accP[kt][0][r] = bias; accP[kt][1][r] = bias;
        }
#pragma unroll
    for (int js = 0; js < 4; ++js) {
        bf16x8 yf[2];
#pragma unroll
        for (int yt = 0; yt < 2; ++yt)
            yf[yt] = *(const bf16x8*)(yb + (y0 + yt * 16 + l15) * NI + js * 32 + 8 * h);
#pragma unroll
        for (int kt = 0; kt < 8; ++kt) {
            bf16x8 af2 = *(const bf16x8*)&SH[(kt * 16 + l15) * KJ_STRIDE + js * 32 + 8 * h];
            accP[kt][0] = __builtin_amdgcn_mfma_f32_16x16x32_bf16(af2, yf[0], accP[kt][0], 0, 0, 0);
            accP[kt][1] = __builtin_amdgcn_mfma_f32_16x16x32_bf16(af2, yf[1], accP[kt][1], 0, 0, 0);
        }
    }
    __syncthreads();   // all waves done reading A2 region

    // ---- P' -> LDS [y][P_STRIDE] bf16 ----
#pragma unroll
    for (int kt = 0; kt < 8; ++kt)
#pragma unroll
        for (int yt = 0; yt < 2; ++yt) {
            unsigned lo = (unsigned)f2bf(accP[kt][yt][0]) | ((unsigned)f2bf(accP[kt][yt][1]) << 16);
            unsigned hi = (unsigned)f2bf(accP[kt][yt][2]) | ((unsigned)f2bf(accP[kt][yt][3]) << 16);
            uint2 v; v.x = lo; v.y = hi;
            *(uint2*)&SH[(y0 + yt * 16 + l15) * P_STRIDE + kt * 16 + 4 * h] = v;
        }

    // z fragments: wave owns 64 z-rows, loaded once (overlaps ds_writes above)
    const int zg = wv & 3, yh = wv >> 2;
    const int z0 = zg * 64;
    short4_t zf[4][8];
#pragma unroll
    for (int zt = 0; zt < 4; ++zt)
#pragma unroll
        for (int kt = 0; kt < 8; ++kt)
            zf[zt][kt] = *(const short4_t*)(zb + (z0 + zt * 16 + l15) * NI + kt * 16 + 4 * h);

    __syncthreads();   // P' visible

    // ---- Phase B: S[y,z] = sum_k z[z,k]*P'[k,y]; wave: 64 z x 128 y ----
    float* outb = out + (size_t)bx * (LL * LL);
#pragma unroll 1
    for (int yti = 0; yti < 8; ++yti) {
        const int yy = yh * 128 + yti * 16 + l15;    // this lane's y (col)
        f32x4 acc2[4];
#pragma unroll
        for (int zt = 0; zt < 4; ++zt) { acc2[zt][0] = 0.f; acc2[zt][1] = 0.f; acc2[zt][2] = 0.f; acc2[zt][3] = 0.f; }
#pragma unroll
        for (int kt = 0; kt < 8; ++kt) {
            short4_t pB = *(const short4_t*)&SH[yy * P_STRIDE + kt * 16 + 4 * h];
#pragma unroll
            for (int zt = 0; zt < 4; ++zt)
                acc2[zt] = __builtin_amdgcn_mfma_f32_16x16x16bf16_1k(zf[zt][kt], pB, acc2[zt], 0, 0, 0);
        }
#pragma unroll
        for (int zt = 0; zt < 4; ++zt)
            *(f32x4*)(outb + (size_t)yy * LL + z0 + zt * 16 + 4 * h) = acc2[zt];
    }
}

extern "C" void kernel_launch(void* const* d_in, const int* in_sizes, int n_in,
                              void* d_out, int out_size, void* d_ws, size_t ws_size,
                              hipStream_t stream) {
    const float* x = (const float*)d_in[0];
    const float* y = (const float*)d_in[1];
    const float* z = (const float*)d_in[2];
    const float* W = (const float*)d_in[3];   // [129][128][129][1] = [129][16512]
    float* out = (float*)d_out;

    unsigned short* yzbf = (unsigned short*)d_ws;            // y:65536 + z:65536
    unsigned short* A2g  = yzbf + 131072;                    // 512*17408 (~17.8 MB)

    stage1_kernel<<<336, 512, 0, stream>>>(W, x, y, z, yzbf, A2g);
    stage2_kernel<<<512, 512, 0, stream>>>(yzbf, yzbf + 65536, A2g, out);
}